// Round 8
// baseline (445.437 us; speedup 1.0000x reference)
//
#include <hip/hip_runtime.h>

// x: (64,3,512,512) fp32 -> conv3x3 VALID + avgpool2x2 + sigmoid + per-batch sum.
// Fused stride-2 4x4 conv: w_eff[ky][kx] = 0.25*sum_{py,px in {0,1}} w[ky-py][kx-px].
//
// R7: ALLOCATOR-PROOF scalar-FMA row streaming.
//  Lesson (R3-R6): hipcc never keeps big load-derived register arrays resident;
//  only loop-carried accumulators are safe, and total live state must stay <90.
//  Structure: lane = pooled col-pair; oc split in 2 chunks of 8 (blockIdx.x,
//  2nd pass L3-resident). Persistent state = 32 acc floats (8 oc x 2 cols x
//  {old,new}) + 8 bias. Per t-step (one input row-pair): for each (par,ic),
//  load 6 x floats (float4+float2, coalesced) and one 64-float wave-uniform
//  weight block (s_load_dwordx16 x4), consume IMMEDIATELY in 128 scalar FMAs.
//  768 FMA : 12 VMEM : 24 SMEM per step, ~87% FMA issue share. No LDS.
//  Row-streaming {old,new} recurrence (verified R4/R5/R6) with role-swapped
//  acc pair (unroll-2) -> no rotate copies.

#define IC 3
#define OCH 16
#define OCC 8       // oc per chunk
#define HH 512
#define WW 512
#define WP 255      // pooled cols
#define L 15        // pooled rows per strip (255 = 15*17)
#define STRIPS 17

__device__ __forceinline__ float fast_sigmoid(float v) {
    float e = __expf(-v);                    // v_exp_f32
    return __builtin_amdgcn_rcpf(1.0f + e);  // v_rcp_f32
}

// ws layout (floats):
//   12 blocks of 64: blk = (chunk*2+par)*3+ic
//     blk[oc8*8 + 0..3] = w_eff[par+2][ic][kx]  ("old": completes pooled row)
//     blk[oc8*8 + 4..7] = w_eff[par  ][ic][kx]  ("new": starts pooled row)
//   bias at ws[768 + oc]   (total 784 floats)
__global__ void build_weff(const float* __restrict__ w,
                           const float* __restrict__ bias,
                           float* __restrict__ ws)
{
    const int i = threadIdx.x;
    for (int idx = i; idx < 768; idx += 256) {
        const int blk   = idx >> 6;       // (chunk*2+par)*3+ic
        const int r     = idx & 63;
        const int oc8   = r >> 3;
        const int which = (r >> 2) & 1;   // 0: old (ky=par+2), 1: new (ky=par)
        const int kx    = r & 3;
        const int ic    = blk % 3;
        const int t2    = blk / 3;        // chunk*2+par
        const int par   = t2 & 1;
        const int chunk = t2 >> 1;
        const int oc    = chunk * OCC + oc8;
        const int ky    = which ? par : (par + 2);
        float s = 0.f;
#pragma unroll
        for (int py = 0; py < 2; ++py) {
            int rr = ky - py;
            if (rr < 0 || rr > 2) continue;
#pragma unroll
            for (int px = 0; px < 2; ++px) {
                int cc = kx - px;
                if (cc < 0 || cc > 2) continue;
                s += w[((oc * IC + ic) * 3 + rr) * 3 + cc];
            }
        }
        ws[idx] = 0.25f * s;
    }
    if (i < OCH) ws[768 + i] = bias[i];
}

// One t-step: input rows 2T,2T+1. AO completes (pooled row T-1), AN starts
// (pooled row T). Weights + x consumed immediately -> nothing to sink.
#define STEP(T, AO, AN, EMIT)                                               \
  {                                                                         \
    _Pragma("unroll")                                                       \
    for (int par = 0; par < 2; ++par) {                                     \
      _Pragma("unroll")                                                     \
      for (int ic = 0; ic < IC; ++ic) {                                     \
        const float* xp = xg + (size_t)ic * (HH * WW)                       \
                             + (size_t)(2 * (T) + par) * WW;                \
        const float4 a  = *(const float4*)xp;                               \
        const float2 tv = *(const float2*)(xp + tail);                      \
        const float xB2 = tv.x, xB3 = tv.y;                                 \
        const float* wb = wbase + (par * IC + ic) * 64;                     \
        _Pragma("unroll")                                                   \
        for (int o = 0; o < OCC; ++o) {                                     \
          const float wo0 = wb[o*8+0], wo1 = wb[o*8+1];                     \
          const float wo2 = wb[o*8+2], wo3 = wb[o*8+3];                     \
          const float wn0 = wb[o*8+4], wn1 = wb[o*8+5];                     \
          const float wn2 = wb[o*8+6], wn3 = wb[o*8+7];                     \
          AO[o][0] += a.x*wo0 + a.y*wo1 + a.z*wo2 + a.w*wo3;                \
          AO[o][1] += a.z*wo0 + a.w*wo1 + xB2*wo2 + xB3*wo3;                \
          AN[o][0] += a.x*wn0 + a.y*wn1 + a.z*wn2 + a.w*wn3;                \
          AN[o][1] += a.z*wn0 + a.w*wn1 + xB2*wn2 + xB3*wn3;                \
        }                                                                   \
      }                                                                     \
    }                                                                       \
    if (EMIT) {                                                             \
      _Pragma("unroll")                                                     \
      for (int o = 0; o < OCC; ++o) {                                       \
        lsA += fast_sigmoid(AO[o][0]);                                      \
        lsB += fast_sigmoid(AO[o][1]);                                      \
      }                                                                     \
    }                                                                       \
    _Pragma("unroll")                                                       \
    for (int o = 0; o < OCC; ++o) { AO[o][0] = bv[o]; AO[o][1] = bv[o]; }   \
  }

__global__ __launch_bounds__(128)
void conv_pool_sig_sum(const float* __restrict__ x,
                       const float* __restrict__ wws,
                       float* __restrict__ out)
{
    const int tid   = threadIdx.x;             // 0..127: pooled cols 2tid, 2tid+1
    const int chunk = blockIdx.x;              // 0,1: oc chunk (adjacent -> L3 reuse)
    const int b     = blockIdx.y;
    const int r0    = blockIdx.z * L;
    const int tail  = (tid < 127) ? 4 : 0;     // lane 127: re-read in-bounds, masked

    const float* xg = x + (size_t)b * (IC * HH * WW)
                        + (size_t)(2 * r0) * WW + 4 * tid;
    const float* wbase = wws + chunk * (2 * IC * 64);

    float bv[OCC];
#pragma unroll
    for (int o = 0; o < OCC; ++o) bv[o] = wws[768 + chunk * OCC + o];

    // persistent state: exactly 32 acc floats + 8 bias (+ lsA/lsB)
    float aX[OCC][2], aY[OCC][2];
#pragma unroll
    for (int o = 0; o < OCC; ++o) {
        aX[o][0] = bv[o]; aX[o][1] = bv[o];
        aY[o][0] = bv[o]; aY[o][1] = bv[o];
    }
    float lsA = 0.f, lsB = 0.f;

    // 16 steps (t=0..15): step t reads input rows 2(r0+t), +1.
    // t=0: aX's "old" half is garbage -> not emitted, reinit'd. Final step's
    // "new" half (next strip's first pooled row) is dropped after the loop.
#pragma unroll 1
    for (int t = 0; t < L; t += 2) {
        STEP(t,     aX, aY, (t > 0))
        STEP(t + 1, aY, aX, true)
    }

    if (2 * tid + 1 >= WP) lsB = 0.f;   // pooled col 255 doesn't exist (lane 127)
    float lsum = lsA + lsB;

    // wave64 butterfly -> 2-wave LDS reduce -> one atomic per block
#pragma unroll
    for (int off = 32; off > 0; off >>= 1)
        lsum += __shfl_xor(lsum, off, 64);

    __shared__ float red[2];
    if ((tid & 63) == 0) red[tid >> 6] = lsum;
    __syncthreads();
    if (tid == 0) atomicAdd(out + b, red[0] + red[1]);
}

extern "C" void kernel_launch(void* const* d_in, const int* in_sizes, int n_in,
                              void* d_out, int out_size, void* d_ws, size_t ws_size,
                              hipStream_t stream) {
    const float* x = (const float*)d_in[0];
    const float* w = (const float*)d_in[1];
    const float* bias = (const float*)d_in[2];
    float* out = (float*)d_out;
    float* wws = (float*)d_ws;  // 784 floats

    hipMemsetAsync(out, 0, out_size * sizeof(float), stream);
    build_weff<<<1, 256, 0, stream>>>(w, bias, wws);

    dim3 grid(2, 64, STRIPS);  // 2 oc-chunks x 64 batches x 17 strips = 2176 blocks
    conv_pool_sig_sum<<<grid, 128, 0, stream>>>(x, wws, out);
}